// Round 11
// baseline (190.127 us; speedup 1.0000x reference)
//
#include <hip/hip_runtime.h>
#include <hip/hip_bf16.h>

// MPNN, R22: MEASUREMENT ROUND.  Seven structural rounds (R15-R21) all landed
// within +-7% of R14's 112.9us while per-kernel durations stayed invisible
// (the harness's ~46us poison fills crowd the rocprof top-5; every kernel of
// ours is <44us).  This round makes the budget visible: each R17b kernel
// (verbatim, proven absmax 0.5) runs its body REP times in-kernel:
//   prep x8, eg x4, nacc x4 (atomic scale 1/(256*rep) -> same value),
//   convert x4, final x4.
// All repeats are idempotent (same values rewritten); eg adds one repeat-
// boundary __syncthreads() (Hs-read vs next-iteration stage(0) DMA write --
// a hazard that only exists under repetition).  Per-kernel time ~= dur/rep.
// Expected total ~380-480us (this round is information, not speed).

typedef short bf16x8  __attribute__((ext_vector_type(8)));
typedef short short4v __attribute__((ext_vector_type(4)));
typedef float f32x4   __attribute__((ext_vector_type(4)));

__device__ inline short f2bf(float x) {                // fp32 -> bf16 RNE
    unsigned u = __builtin_bit_cast(unsigned, x);
    return (short)((u + 0x7fffu + ((u >> 16) & 1u)) >> 16);
}
__device__ inline float bf2f(short b) {
    return __builtin_bit_cast(float, (unsigned)((unsigned short)b) << 16);
}
__device__ inline void cp16_async(const char* g, char* l) {
    __builtin_amdgcn_global_load_lds(
        (const __attribute__((address_space(1))) unsigned int*)g,
        (__attribute__((address_space(3))) unsigned int*)l, 16, 0, 0);
}

// --------------------------------------------------------------- core128
// R17b verbatim.  Ends with __syncthreads().
__device__ __forceinline__ void core128(
    const short* __restrict__ Ap, int lda, const short* __restrict__ Bp, int ldb,
    int kbeg, int kend, int m0, int n0, short* Sf, f32x4 acc[4][4], int t)
{
    const int l = t & 63, lr = l & 15, q = l >> 4;
    const int w = t >> 6, wm = w >> 1, wn = w & 1;
    const int wub = t & ~63;

    auto stage = [&](int buf, int k0) {
        #pragma unroll
        for (int it = 0; it < 4; ++it) {
            int idx = it * 256 + t, r = idx >> 3, s = idx & 7;
            cp16_async((const char*)(Ap + (size_t)(m0 + r) * lda + k0) + s * 16,
                       (char*)(Sf + buf * 16384) + (size_t)(it * 256 + wub) * 16);
        }
        #pragma unroll
        for (int it = 0; it < 4; ++it) {
            int idx = it * 256 + t, r = idx >> 3, s = idx & 7;
            cp16_async((const char*)(Bp + (size_t)(n0 + r) * ldb + k0) + s * 16,
                       (char*)(Sf + buf * 16384 + 8192) + (size_t)(it * 256 + wub) * 16);
        }
    };

    stage(0, kbeg);
    __syncthreads();
    int cur = 0;
    for (int k0 = kbeg; k0 < kend; k0 += 64) {
        if (k0 + 64 < kend) stage(cur ^ 1, k0 + 64);
        const short* As = Sf + cur * 16384;
        const short* Bs = As + 8192;
        #pragma unroll
        for (int ks = 0; ks < 2; ++ks) {
            bf16x8 af[4], bfr[4];
            #pragma unroll
            for (int mt = 0; mt < 4; ++mt) {
                int ar = wm * 64 + mt * 16 + lr;
                af[mt] = *(const bf16x8*)&As[ar * 64 + (((ks*4 + q) ^ (ar & 7)) << 3)];
            }
            #pragma unroll
            for (int nt = 0; nt < 4; ++nt) {
                int br = wn * 64 + nt * 16 + lr;
                bfr[nt] = *(const bf16x8*)&Bs[br * 64 + (((ks*4 + q) ^ (br & 7)) << 3)];
            }
            #pragma unroll
            for (int mt = 0; mt < 4; ++mt)
                #pragma unroll
                for (int nt = 0; nt < 4; ++nt)
                    acc[mt][nt] = __builtin_amdgcn_mfma_f32_16x16x32_bf16(
                        af[mt], bfr[nt], acc[mt][nt], 0, 0, 0);
        }
        __syncthreads();
        cur ^= 1;
    }
}

// ------------------------------------------------------------------ prep_x8
// R17b prep_all body, repeated rep times (idempotent).
__global__ void prep_x8(const float* __restrict__ X, short* __restrict__ h,
                        const float* __restrict__ W1, const float* __restrict__ W2,
                        const float* __restrict__ Wo,
                        short* __restrict__ Wt1, short* __restrict__ Wt2,
                        short* __restrict__ Wto1, short* __restrict__ Wto2,
                        short* __restrict__ Bt4, float* __restrict__ Nacc, int rep)
{
    __shared__ short tile[32][33];
    const int tx = threadIdx.x, ty = threadIdx.y;      // 32 x 8
    for (int rr = 0; rr < rep; ++rr) {
        if (blockIdx.y < 8) {
            const int r0 = blockIdx.x * 32, c0 = blockIdx.y * 32;
            #pragma unroll
            for (int i = 0; i < 4; ++i) {
                int row = ty + i * 8;
                short b = f2bf(X[(size_t)(r0 + row) * 256 + c0 + tx]);
                int slot = ((((c0 & 32) + tx) >> 3) ^ ((r0 + row) & 7));
                h[(size_t)(r0 + row) * 768 + (c0 & ~63) + slot * 8 + (tx & 7)] = b;
            }
        } else {
            int tw = (blockIdx.y - 8) * 256 + blockIdx.x;
            if (tw >= 320) {                           // zero Nacc
                int i0 = (tw - 320) * 256 + ty * 32 + tx;
                for (int i = i0; i < 131072; i += 49152) Nacc[i] = 0.f;
            } else {
                const float* src; short* dst; int ldwt, dk0, kx, ny;
                if (tw < 64)       { src = W1; dst = Wt1; ldwt = 256;
                                     kx = tw >> 3; ny = tw & 7; dk0 = kx * 32; }
                else if (tw < 128) { int u = tw - 64; src = W2; dst = Wt2;
                                     ldwt = 256; kx = u >> 3; ny = u & 7; dk0 = kx * 32; }
                else               { int u = tw - 128; int g = u >> 6; int rem = u & 63;
                                     kx = rem >> 3; ny = rem & 7;
                                     src = Wo + (size_t)g * 65536;
                                     if (g == 0) { dst = Bt4; ldwt = 768; dk0 = kx * 32; }
                                     else        { dst = (g == 1) ? Wto1 : Wto2;
                                                   ldwt = 256; dk0 = kx * 32; } }
                const int k0l = kx * 32, n0 = ny * 32;
                #pragma unroll
                for (int i = 0; i < 4; ++i) {
                    int row = ty + i * 8;
                    tile[row][tx] = f2bf(src[(size_t)(k0l + row) * 256 + n0 + tx]);
                }
                __syncthreads();
                #pragma unroll
                for (int i = 0; i < 4; ++i) {
                    int row = ty + i * 8;
                    int n = n0 + row;
                    int slot = ((((dk0 & 32) + tx) >> 3) ^ (n & 7));
                    dst[(size_t)n * ldwt + (dk0 & ~63) + slot * 8 + (tx & 7)] =
                        tile[tx][row];
                }
                __syncthreads();               // repeat-boundary (tile WAR)
            }
        }
    }
}

// ------------------------------------------------------------------ eg_x4
// R17b job0 body, repeated (idempotent: rewrites same h/e/G values).
__global__ __launch_bounds__(256, 1)
void eg_x4(short* __restrict__ h,
           const short* __restrict__ Wt1, const short* __restrict__ Wt2,
           const short* __restrict__ Wto1, const short* __restrict__ Wto2,
           const float* __restrict__ b1, const float* __restrict__ b2,
           short* __restrict__ e1t, short* __restrict__ e2t,
           short* __restrict__ G1t, short* __restrict__ G2t, int rep)
{
    const int z = blockIdx.z;
    const int mode = (z < 2) ? 1 : 3;
    const int sim  = z & 1;
    const short* Bp   = (z == 0) ? Wt1 : (z == 1) ? Wt2 : (z == 2) ? Wto1 : Wto2;
    const float* bias = (z == 0) ? b1  : (z == 1) ? b2  : nullptr;
    short* et         = (z == 0) ? e1t : (z == 1) ? e2t : (z == 2) ? G1t : G2t;

    const int m0 = blockIdx.x * 128, n0 = blockIdx.y * 128;
    const int t = threadIdx.x;
    const int l = t & 63, lr = l & 15, q = l >> 4;
    const int w = t >> 6, wm = w >> 1, wn = w & 1;

    __shared__ __attribute__((aligned(16))) short S[32768];

    for (int rr = 0; rr < rep; ++rr) {
        f32x4 acc[4][4];
        #pragma unroll
        for (int i = 0; i < 4; ++i)
            #pragma unroll
            for (int j = 0; j < 4; ++j) acc[i][j] = f32x4{0.f, 0.f, 0.f, 0.f};

        core128(h, 768, Bp, 256, 0, 256, m0, n0, S, acc, t);

        short* Hs = S;
        short* Ts = S + 16384;
        #pragma unroll
        for (int mt = 0; mt < 4; ++mt)
            #pragma unroll
            for (int nt = 0; nt < 4; ++nt) {
                int n_loc = wn * 64 + nt * 16 + lr;
                float bb = (mode == 1) ? bias[n0 + n_loc] : 0.f;
                short vb[4];
                #pragma unroll
                for (int r = 0; r < 4; ++r) {
                    float v = acc[mt][nt][r] + bb;
                    if (mode == 1) v = v > 0.f ? v : 0.f;
                    vb[r] = f2bf(v);
                    if (mode == 1) {
                        int m_loc = wm * 64 + mt * 16 + q * 4 + r;
                        Hs[m_loc * 128 + n_loc] = vb[r];
                    }
                }
                int gm = wm * 8 + mt * 2 + (q >> 1);
                short4v pk = { vb[0], vb[1], vb[2], vb[3] };
                *(short4v*)&Ts[n_loc * 128 + ((gm >> 3) << 6)
                               + (((gm & 7) ^ (n_loc & 7)) << 3) + ((q & 1) << 2)] = pk;
            }
        __syncthreads();
        if (mode == 1) {
            const int cb = 256 + sim * 256 + n0;
            for (int i = t; i < 2048; i += 256) {
                int ml = i >> 4, g = i & 15;
                bf16x8 hv = *(const bf16x8*)&Hs[ml * 128 + g * 8];
                *(bf16x8*)(h + (size_t)(m0 + ml) * 768 + cb + ((g >> 3) << 6)
                           + (((g & 7) ^ (ml & 7)) << 3)) = hv;
            }
        }
        for (int i = t; i < 2048; i += 256) {
            int nl = i >> 4, s = i & 15;
            bf16x8 tv = *(const bf16x8*)&Ts[nl * 128 + s * 8];
            *(bf16x8*)(et + (size_t)(n0 + nl) * 8192 + m0 + s * 8) = tv;
        }
        __syncthreads();                       // repeat-boundary (Hs/Ts WAR
                                               // vs next core128 stage DMA)
    }
}

// ---------------------------------------------------------- nacc_x4
// R17b job1 body, repeated; atomic scale 1/(256*rep) -> same accumulated N.
__global__ __launch_bounds__(256, 1)
void nacc_x4(const short* __restrict__ e1t, const short* __restrict__ e2t,
             const short* __restrict__ G1t, const short* __restrict__ G2t,
             float* __restrict__ Nacc, int rep)
{
    const int z = blockIdx.z;
    const int sim = z & 1;
    const int kbeg = (z >> 1) * 512;
    const short* Ap = sim ? G2t : G1t;
    const short* Bp = sim ? e2t : e1t;
    const int m0 = blockIdx.x * 128, n0 = blockIdx.y * 128;
    const int t = threadIdx.x;
    const int l = t & 63, lr = l & 15, q = l >> 4;
    const int w = t >> 6, wm = w >> 1, wn = w & 1;

    __shared__ __attribute__((aligned(16))) short S[32768];

    const float scale = 1.0f / (256.0f * (float)rep);
    for (int rr = 0; rr < rep; ++rr) {
        f32x4 acc[4][4];
        #pragma unroll
        for (int i = 0; i < 4; ++i)
            #pragma unroll
            for (int j = 0; j < 4; ++j) acc[i][j] = f32x4{0.f, 0.f, 0.f, 0.f};

        core128(Ap, 8192, Bp, 8192, kbeg, kbeg + 512, m0, n0, S, acc, t);

        float* Mo = Nacc + (size_t)sim * 65536;
        #pragma unroll
        for (int mt = 0; mt < 4; ++mt)
            #pragma unroll
            for (int nt = 0; nt < 4; ++nt)
                #pragma unroll
                for (int r = 0; r < 4; ++r) {
                    int m = m0 + wm * 64 + mt * 16 + q * 4 + r;
                    int n = n0 + wn * 64 + nt * 16 + lr;
                    atomicAdd(&Mo[(size_t)m * 256 + n], acc[mt][nt][r] * scale);
                }
    }
}

// ---------------------------------------------------------- conv_x4
// R17b convert_n body, repeated (idempotent).
__global__ void conv_x4(const float* __restrict__ Nacc, short* __restrict__ Bt4,
                        int rep)
{
    for (int rr = 0; rr < rep; ++rr) {
        int gid = blockIdx.x * 256 + threadIdx.x;      // 0..16383
        int sim = gid >> 13, rem = gid & 8191;
        int n = rem >> 5, g = rem & 31;
        const float* np = Nacc + (size_t)sim * 65536 + (size_t)n * 256 + g * 8;
        f32x4 va = *(const f32x4*)np;
        f32x4 vb = *(const f32x4*)(np + 4);
        bf16x8 pk;
        pk[0] = f2bf(va[0]); pk[1] = f2bf(va[1]);
        pk[2] = f2bf(va[2]); pk[3] = f2bf(va[3]);
        pk[4] = f2bf(vb[0]); pk[5] = f2bf(vb[1]);
        pk[6] = f2bf(vb[2]); pk[7] = f2bf(vb[3]);
        int k = 256 + sim * 256 + g * 8;
        int slot = (g & 7) ^ (n & 7);
        *(bf16x8*)(Bt4 + (size_t)n * 768 + (k & ~63) + slot * 8) = pk;
    }
}

// ---------------------------------------------------------- final_x4
// R17b job2 body, repeated (idempotent).
__global__ __launch_bounds__(256, 1)
void final_x4(const short* __restrict__ h, const short* __restrict__ Bt4,
              const float* __restrict__ bov, float* __restrict__ outf, int rep)
{
    const int m0 = blockIdx.x * 128, n0 = blockIdx.y * 128;
    const int t = threadIdx.x;
    const int l = t & 63, lr = l & 15, q = l >> 4;
    const int w = t >> 6, wm = w >> 1, wn = w & 1;

    __shared__ __attribute__((aligned(16))) short S[32768];

    for (int rr = 0; rr < rep; ++rr) {
        f32x4 acc[4][4];
        #pragma unroll
        for (int i = 0; i < 4; ++i)
            #pragma unroll
            for (int j = 0; j < 4; ++j) acc[i][j] = f32x4{0.f, 0.f, 0.f, 0.f};

        core128(h, 768, Bt4, 768, 0, 768, m0, n0, S, acc, t);

        #pragma unroll
        for (int mt = 0; mt < 4; ++mt)
            #pragma unroll
            for (int nt = 0; nt < 4; ++nt)
                #pragma unroll
                for (int r = 0; r < 4; ++r) {
                    int m = m0 + wm * 64 + mt * 16 + q * 4 + r;
                    int n = n0 + wn * 64 + nt * 16 + lr;
                    float v = acc[mt][nt][r] + bov[n];
                    outf[(size_t)m * 256 + n] = v > 0.f ? v : 0.f;
                }
    }
}

// ---------------------------------------------------------------- launch
extern "C" void kernel_launch(void* const* d_in, const int* in_sizes, int n_in,
                              void* d_out, int out_size, void* d_ws, size_t ws_size,
                              hipStream_t stream)
{
    const float* edge_x = (const float*)d_in[0];
    const float* W1 = (const float*)d_in[1];
    const float* b1 = (const float*)d_in[2];
    const float* W2 = (const float*)d_in[3];
    const float* b2 = (const float*)d_in[4];
    const float* Wo = (const float*)d_in[5];
    const float* bo = (const float*)d_in[6];

    // workspace (~31 MB)
    char* ws = (char*)d_ws;
    short* h    = (short*)ws;                    // [8192][768] bf16 swz  12,582,912
    short* e1t  = (short*)(ws + 12582912);       // [256][8192] bf16 swz   4,194,304
    short* e2t  = (short*)(ws + 16777216);       // [256][8192] bf16 swz   4,194,304
    short* G1t  = (short*)(ws + 20971520);       // [256][8192] bf16 swz   4,194,304
    short* G2t  = (short*)(ws + 25165824);       // [256][8192] bf16 swz   4,194,304
    short* Wt1  = (short*)(ws + 29360128);       // [256][256]  bf16 swz     131,072
    short* Wt2  = (short*)(ws + 29491200);       // [256][256]  bf16 swz     131,072
    short* Wto1 = (short*)(ws + 29622272);       // [256][256]  bf16 swz     131,072
    short* Wto2 = (short*)(ws + 29753344);       // [256][256]  bf16 swz     131,072
    short* Bt4  = (short*)(ws + 29884416);       // [256][768]  bf16 swz     393,216
    float* Nacc = (float*)(ws + 30277632);       // [2][256][256] fp32       524,288

    float* out = (float*)d_out;

    prep_x8<<<dim3(256, 10), dim3(32, 8), 0, stream>>>(
        edge_x, h, W1, W2, Wo, Wt1, Wt2, Wto1, Wto2, Bt4, Nacc, 8);

    eg_x4<<<dim3(64, 2, 4), 256, 0, stream>>>(
        h, Wt1, Wt2, Wto1, Wto2, b1, b2, e1t, e2t, G1t, G2t, 4);

    nacc_x4<<<dim3(2, 2, 32), 256, 0, stream>>>(e1t, e2t, G1t, G2t, Nacc, 4);

    conv_x4<<<dim3(64), 256, 0, stream>>>(Nacc, Bt4, 4);

    final_x4<<<dim3(64, 2), 256, 0, stream>>>(h, Bt4, bo, out, 4);
}